// Round 2
// baseline (724.348 us; speedup 1.0000x reference)
//
#include <hip/hip_runtime.h>
#include <hip/hip_bf16.h>
#include <stdint.h>

#define K_DIM 40960
#define NROWS 8192
#define ACCH 256
#define KSPLIT 4
#define KCHUNK (K_DIM / KSPLIT)   // 10240
#define BM 256
#define BK 64
#define NT (KCHUNK / BK)          // 160

typedef float f32x4 __attribute__((ext_vector_type(4)));
typedef _Float16 f16x8 __attribute__((ext_vector_type(8)));

// RNE f32 -> f16 pair pack (v_cvt_f16_f32 is RNE by default; RTZ would bias)
__device__ __forceinline__ uint32_t pack2_f16(float a, float b) {
  _Float16 ha = (_Float16)a, hb = (_Float16)b;
  uint16_t ua = __builtin_bit_cast(uint16_t, ha);
  uint16_t ub = __builtin_bit_cast(uint16_t, hb);
  return (uint32_t)ua | ((uint32_t)ub << 16);
}

__device__ __forceinline__ void gload_lds16(const void* g, void* l) {
  __builtin_amdgcn_global_load_lds((const __attribute__((address_space(1))) uint32_t*)g,
                                   (__attribute__((address_space(3))) uint32_t*)l, 16, 0, 0);
}

// ---------------- kernel 1: fp32 -> fp16 weight conversion (RNE) ----------------
__global__ void convert_w_kernel(const float* __restrict__ ww, const float* __restrict__ wb,
                                 uint16_t* __restrict__ dst) {
  uint32_t gid = blockIdx.x * blockDim.x + threadIdx.x;
  uint64_t e = (uint64_t)gid * 8u;
  const uint64_t half = (uint64_t)ACCH * K_DIM;
  const float* src = (e < half) ? (ww + e) : (wb + (e - half));
  float4 f0 = *(const float4*)src;
  float4 f1 = *(const float4*)(src + 4);
  uint4 o;
  o.x = pack2_f16(f0.x, f0.y);
  o.y = pack2_f16(f0.z, f0.w);
  o.z = pack2_f16(f1.x, f1.y);
  o.w = pack2_f16(f1.z, f1.w);
  *(uint4*)(dst + e) = o;
}

// ---------------- kernel 2: split-K feature-transformer GEMM (fp16 MFMA) ----------
// grid = 32 mtiles x 2 colors x 4 ksplits = 256 blocks, 512 threads (8 waves, 2x4)
// tile: 256 rows x 256 cols x BK=64. A: fp32 global -> reg -> f16 -> LDS.
// B: f16 (pre-converted) via global_load_lds dwordx4. Double-buffered 128 KiB LDS.
__global__ __launch_bounds__(512, 2) void ft_gemm(
    const float* __restrict__ featW, const float* __restrict__ featB,
    const uint16_t* __restrict__ wts, float* __restrict__ partials)
{
  extern __shared__ char smem[];
  const int tid = threadIdx.x;
  const int bid = blockIdx.x;
  const int mt  = bid & 31;
  const int cc  = (bid >> 5) & 1;
  const int ksp = bid >> 6;
  const float*    feat = cc ? featB : featW;
  const uint16_t* wp   = wts + (uint64_t)cc * ACCH * K_DIM;
  const int m0 = mt * BM;
  const int k0 = ksp * KCHUNK;

  const int wid  = tid >> 6;
  const int lane = tid & 63;
  const int wm   = wid >> 2;   // 0..1
  const int wn   = wid & 3;    // 0..3
  const int lrow = lane & 15;
  const int lk   = lane >> 4;  // 0..3

  // A staging: 4 segments of 8 floats per thread; segment p = base + p*64 rows
  const int ar0 = tid >> 3, as0 = tid & 7;
  const float* aSrc0 = feat + (uint64_t)(m0 + ar0) * K_DIM + k0 + as0 * 8;
  const int aOff0 = ar0 * 128 + as0 * 16;   // LDS byte offset, row pitch 128B

  // B staging: 4 global_load_lds(16B) per thread; instr i = base + i*64 rows
  const int gsegB = wid * 64 + lane;
  const int br0 = gsegB >> 3, bs0 = gsegB & 7;
  const uint16_t* bSrc0 = wp + (uint64_t)br0 * K_DIM + k0 + bs0 * 8;

  float4 av[4][2];
  auto loadA = [&]() {
    #pragma unroll
    for (int p = 0; p < 4; ++p) {
      const float* s = aSrc0 + (uint64_t)p * 64u * K_DIM;
      av[p][0] = *(const float4*)(s);
      av[p][1] = *(const float4*)(s + 4);
    }
    aSrc0 += BK;
  };
  auto writeA = [&](int buf) {
    #pragma unroll
    for (int p = 0; p < 4; ++p) {
      uint4 o;
      o.x = pack2_f16(av[p][0].x, av[p][0].y);
      o.y = pack2_f16(av[p][0].z, av[p][0].w);
      o.z = pack2_f16(av[p][1].x, av[p][1].y);
      o.w = pack2_f16(av[p][1].z, av[p][1].w);
      *(uint4*)(smem + buf * 65536 + aOff0 + p * 8192) = o;
    }
  };
  auto issueB = [&](int buf) {
    #pragma unroll
    for (int i = 0; i < 4; ++i) {
      gload_lds16(bSrc0 + (uint64_t)i * 64u * K_DIM,
                  smem + buf * 65536 + 32768 + (i * 8 + wid) * 1024);
    }
    bSrc0 += BK;
  };

  // prologue
  loadA();        // A(0)
  issueB(0);      // B(0) -> buf0
  writeA(0);      // cvt+write A(0) -> buf0
  loadA();        // A(1)
  __syncthreads();

  f32x4 acc[8][4];
  #pragma unroll
  for (int m = 0; m < 8; ++m)
    #pragma unroll
    for (int n = 0; n < 4; ++n)
      acc[m][n] = (f32x4){0.f, 0.f, 0.f, 0.f};

  for (int t = 0; t < NT; ++t) {
    const int cur = t & 1, nxt = cur ^ 1;
    if (t < NT - 1) {
      writeA(nxt);            // A(t+1) -> next buffer (readers finished at last barrier)
      issueB(nxt);            // B(t+1) in flight, overlaps MFMA below
      if (t < NT - 2) loadA();// A(t+2) -> regs, overlaps MFMA below
    }
    const char* Ab = smem + cur * 65536;
    const char* Bb = smem + cur * 65536 + 32768;
    #pragma unroll
    for (int ksub = 0; ksub < 2; ++ksub) {
      f16x8 af[8], bfr[4];
      #pragma unroll
      for (int m = 0; m < 8; ++m)
        af[m] = *(const f16x8*)(Ab + (wm * 128 + m * 16 + lrow) * 128 + ksub * 64 + lk * 16);
      #pragma unroll
      for (int n = 0; n < 4; ++n)
        bfr[n] = *(const f16x8*)(Bb + (wn * 64 + n * 16 + lrow) * 128 + ksub * 64 + lk * 16);
      #pragma unroll
      for (int m = 0; m < 8; ++m)
        #pragma unroll
        for (int n = 0; n < 4; ++n)
          acc[m][n] = __builtin_amdgcn_mfma_f32_16x16x32_f16(af[m], bfr[n], acc[m][n], 0, 0, 0);
    }
    __syncthreads();          // drains vmcnt/lgkm: buf[nxt] complete for next iter
  }

  // epilogue: write fp32 partials [color*KSPLIT+ksp][8192][256]
  float* pbase = partials + ((uint64_t)(cc * KSPLIT + ksp) * NROWS + m0) * ACCH;
  #pragma unroll
  for (int m = 0; m < 8; ++m) {
    #pragma unroll
    for (int n = 0; n < 4; ++n) {
      int row = wm * 128 + m * 16 + lk * 4;
      int col = wn * 64 + n * 16 + lrow;
      float* dst = pbase + (uint64_t)row * ACCH + col;
      dst[0]        = acc[m][n][0];
      dst[ACCH]     = acc[m][n][1];
      dst[2 * ACCH] = acc[m][n][2];
      dst[3 * ACCH] = acc[m][n][3];
    }
  }
}

// ---------------- kernel 3: reduce partials + stm-mix + clip + MLP tail (all fp32) ----
// 512 blocks x 128 threads; each block: 16 rows.
__global__ __launch_bounds__(128) void tail_kernel(
    const float* __restrict__ partials, const float* __restrict__ stm,
    const float* __restrict__ bw, const float* __restrict__ bb,
    const float* __restrict__ w1, const float* __restrict__ b1,
    const float* __restrict__ w2, const float* __restrict__ b2,
    const float* __restrict__ w_out, const float* __restrict__ b_out,
    float* __restrict__ out)
{
  __shared__ float in1[16 * 513];   // pitch 513: conflict-free cross-row reads
  __shared__ float out1c[16 * 33];
  const int t = threadIdx.x;
  const int b0 = blockIdx.x * 16;

  // phase 1: reduce split-K partials, stm-mix, clip -> in1[16][512]
  for (int it = 0; it < 32; ++it) {
    int item = t + it * 128;        // 0..4095
    int jc = item & 255;
    int rr = item >> 8;             // 0..15
    int b  = b0 + rr;
    float wsum = bw[jc], bsum = bb[jc];
    #pragma unroll
    for (int k = 0; k < KSPLIT; ++k) {
      wsum += partials[((uint64_t)(0 * KSPLIT + k) * NROWS + b) * ACCH + jc];
      bsum += partials[((uint64_t)(1 * KSPLIT + k) * NROWS + b) * ACCH + jc];
    }
    float s = stm[b];
    float lo = (1.f - s) * wsum + s * bsum;
    float hi = (1.f - s) * bsum + s * wsum;
    in1[rr * 513 + jc]       = fminf(fmaxf(lo, 0.f), 1.f);
    in1[rr * 513 + 256 + jc] = fminf(fmaxf(hi, 0.f), 1.f);
  }
  __syncthreads();

  // layer 1: 512 -> 32, thread (row rl, o-group og) computes o = og*4+oi
  const int rl = t >> 3, og = t & 7;
  float a1[4] = {0.f, 0.f, 0.f, 0.f};
  for (int j = 0; j < 512; j += 4) {
    float v0 = in1[rl * 513 + j];
    float v1 = in1[rl * 513 + j + 1];
    float v2 = in1[rl * 513 + j + 2];
    float v3 = in1[rl * 513 + j + 3];
    #pragma unroll
    for (int oi = 0; oi < 4; ++oi) {
      const float4 wv = *(const float4*)(w1 + (og * 4 + oi) * 512 + j);
      a1[oi] += v0 * wv.x + v1 * wv.y + v2 * wv.z + v3 * wv.w;
    }
  }
  #pragma unroll
  for (int oi = 0; oi < 4; ++oi) {
    int o = og * 4 + oi;
    out1c[rl * 33 + o] = fminf(fmaxf(a1[oi] + b1[o], 0.f), 1.f);
  }
  __syncthreads();

  // layer 2: 32 -> 32
  float a2[4] = {0.f, 0.f, 0.f, 0.f};
  for (int j = 0; j < 32; ++j) {
    float v = out1c[rl * 33 + j];
    #pragma unroll
    for (int oi = 0; oi < 4; ++oi) a2[oi] += v * w2[(og * 4 + oi) * 32 + j];
  }
  // layer 3: 32 -> 1 (clip then dot w_out), reduce across the 8 og lanes
  float p = 0.f;
  #pragma unroll
  for (int oi = 0; oi < 4; ++oi) {
    int o = og * 4 + oi;
    p += fminf(fmaxf(a2[oi] + b2[o], 0.f), 1.f) * w_out[o];
  }
  p += __shfl_xor(p, 1, 64);
  p += __shfl_xor(p, 2, 64);
  p += __shfl_xor(p, 4, 64);
  if (og == 0) out[b0 + rl] = p + b_out[0];
}

extern "C" void kernel_launch(void* const* d_in, const int* in_sizes, int n_in,
                              void* d_out, int out_size, void* d_ws, size_t ws_size,
                              hipStream_t stream) {
  (void)in_sizes; (void)n_in; (void)out_size; (void)ws_size;
  const float* wfeat   = (const float*)d_in[0];
  const float* bfeat   = (const float*)d_in[1];
  const float* stm     = (const float*)d_in[2];
  const float* w_white = (const float*)d_in[3];
  const float* b_white = (const float*)d_in[4];
  const float* w_black = (const float*)d_in[5];
  const float* b_black = (const float*)d_in[6];
  const float* w1      = (const float*)d_in[7];
  const float* b1      = (const float*)d_in[8];
  const float* w2      = (const float*)d_in[9];
  const float* b2      = (const float*)d_in[10];
  const float* w_out   = (const float*)d_in[11];
  const float* b_out   = (const float*)d_in[12];
  float* out = (float*)d_out;

  uint16_t* wf16     = (uint16_t*)d_ws;                                   // 41,943,040 B
  float*    partials = (float*)((char*)d_ws + (uint64_t)2 * ACCH * K_DIM * 2); // 67,108,864 B

  // kernel 1: weights fp32 -> fp16 (2*256*40960 / 8 per thread = 2,621,440 threads)
  convert_w_kernel<<<10240, 256, 0, stream>>>(w_white, w_black, wf16);

  // kernel 2: main GEMM, 128 KiB dynamic LDS
  (void)hipFuncSetAttribute((const void*)ft_gemm,
                            hipFuncAttributeMaxDynamicSharedMemorySize, 131072);
  ft_gemm<<<256, 512, 131072, stream>>>(wfeat, bfeat, wf16, partials);

  // kernel 3: fused reduce + mix + clip + MLP
  tail_kernel<<<512, 128, 0, stream>>>(partials, stm, b_white, b_black,
                                       w1, b1, w2, b2, w_out, b_out, out);
}

// Round 3
// 646.919 us; speedup vs baseline: 1.1197x; 1.1197x over previous
//
#include <hip/hip_runtime.h>
#include <hip/hip_bf16.h>
#include <stdint.h>

#define K_DIM 40960
#define NROWS 8192
#define ACCH 256
#define KSPLIT 4
#define KCHUNK (K_DIM / KSPLIT)   // 10240
#define BM 256
#define BK 64
#define NT (KCHUNK / BK)          // 160

typedef float f32x4 __attribute__((ext_vector_type(4)));
typedef _Float16 f16x8 __attribute__((ext_vector_type(8)));

// RNE f32 -> f16 pair pack (v_cvt_f16_f32 is RNE by default; RTZ would bias)
__device__ __forceinline__ uint32_t pack2_f16(float a, float b) {
  _Float16 ha = (_Float16)a, hb = (_Float16)b;
  uint16_t ua = __builtin_bit_cast(uint16_t, ha);
  uint16_t ub = __builtin_bit_cast(uint16_t, hb);
  return (uint32_t)ua | ((uint32_t)ub << 16);
}

__device__ __forceinline__ void gload_lds16(const void* g, void* l) {
  __builtin_amdgcn_global_load_lds((const __attribute__((address_space(1))) uint32_t*)g,
                                   (__attribute__((address_space(3))) uint32_t*)l, 16, 0, 0);
}

// ---------------- kernel 1: fp32 -> fp16 weight conversion (RNE) ----------------
__global__ void convert_w_kernel(const float* __restrict__ ww, const float* __restrict__ wb,
                                 uint16_t* __restrict__ dst) {
  uint32_t gid = blockIdx.x * blockDim.x + threadIdx.x;
  uint64_t e = (uint64_t)gid * 8u;
  const uint64_t half = (uint64_t)ACCH * K_DIM;
  const float* src = (e < half) ? (ww + e) : (wb + (e - half));
  float4 f0 = *(const float4*)src;
  float4 f1 = *(const float4*)(src + 4);
  uint4 o;
  o.x = pack2_f16(f0.x, f0.y);
  o.y = pack2_f16(f0.z, f0.w);
  o.z = pack2_f16(f1.x, f1.y);
  o.w = pack2_f16(f1.z, f1.w);
  *(uint4*)(dst + e) = o;
}

// ---------------- kernel 2: split-K feature-transformer GEMM (fp16 MFMA) ----------
// grid = 256 blocks, 512 threads (8 waves, 2x4). tile 256x256xBK64, dbuf 128 KiB LDS.
// T2 XOR-swizzle (slot ^= row&7, 16B slots) on A (swizzled ds_write) and B
// (pre-swizzled GLOBAL source + linear global_load_lds dest — rule #21).
// XCD remap: all 32 blocks sharing a (color,ksplit) B-panel land on one XCD L2.
__global__ __launch_bounds__(512, 2) void ft_gemm(
    const float* __restrict__ featW, const float* __restrict__ featB,
    const uint16_t* __restrict__ wts, float* __restrict__ partials)
{
  extern __shared__ char smem[];
  const int tid = threadIdx.x;
  const int bid = blockIdx.x;
  // XCD-aware remap: (cc,ksp) = bid&7 so same B-panel stays on one XCD (bid%8 rr)
  const int mt  = bid >> 3;
  const int cc  = bid & 1;
  const int ksp = (bid >> 1) & 3;
  const float*    feat = cc ? featB : featW;
  const uint16_t* wp   = wts + (uint64_t)cc * ACCH * K_DIM;
  const int m0 = mt * BM;
  const int k0 = ksp * KCHUNK;

  const int wid  = tid >> 6;
  const int lane = tid & 63;
  const int wm   = wid >> 2;   // 0..1
  const int wn   = wid & 3;    // 0..3
  const int lrow = lane & 15;
  const int lk   = lane >> 4;  // 0..3

  // A staging: 4 segments of 8 floats per thread; segment p = base + p*64 rows
  const int ar0 = tid >> 3, as0 = tid & 7;
  const float* aSrc0 = feat + (uint64_t)(m0 + ar0) * K_DIM + k0 + as0 * 8;
  // swizzled LDS byte offset: slot as0 ^ (row&7), row pitch 128B
  const int aOff0 = ar0 * 128 + ((as0 ^ (ar0 & 7)) * 16);

  // B staging: 4 global_load_lds(16B) per thread; instr i = base + i*64 rows.
  // LDS dest linear; global source pre-swizzled: chunk = (l&7) ^ (row&7)
  const int gsegB = wid * 64 + lane;
  const int br0 = gsegB >> 3;
  const int bs0 = (gsegB & 7) ^ (br0 & 7);
  const uint16_t* bSrc0 = wp + (uint64_t)br0 * K_DIM + k0 + bs0 * 8;

  float4 av[4][2];
  auto loadA = [&]() {
    #pragma unroll
    for (int p = 0; p < 4; ++p) {
      const float* s = aSrc0 + (uint64_t)p * 64u * K_DIM;
      av[p][0] = *(const float4*)(s);
      av[p][1] = *(const float4*)(s + 4);
    }
    aSrc0 += BK;
  };
  auto writeA = [&](int buf) {
    #pragma unroll
    for (int p = 0; p < 4; ++p) {
      uint4 o;
      o.x = pack2_f16(av[p][0].x, av[p][0].y);
      o.y = pack2_f16(av[p][0].z, av[p][0].w);
      o.z = pack2_f16(av[p][1].x, av[p][1].y);
      o.w = pack2_f16(av[p][1].z, av[p][1].w);
      *(uint4*)(smem + buf * 65536 + aOff0 + p * 8192) = o;
    }
  };
  auto issueB = [&](int buf) {
    #pragma unroll
    for (int i = 0; i < 4; ++i) {
      gload_lds16(bSrc0 + (uint64_t)i * 64u * K_DIM,
                  smem + buf * 65536 + 32768 + (i * 8 + wid) * 1024);
    }
    bSrc0 += BK;
  };

  // prologue
  loadA();        // A(0)
  issueB(0);      // B(0) -> buf0
  writeA(0);      // cvt+write A(0) -> buf0
  loadA();        // A(1)
  __syncthreads();

  f32x4 acc[8][4];
  #pragma unroll
  for (int m = 0; m < 8; ++m)
    #pragma unroll
    for (int n = 0; n < 4; ++n)
      acc[m][n] = (f32x4){0.f, 0.f, 0.f, 0.f};

  for (int t = 0; t < NT; ++t) {
    const int cur = t & 1, nxt = cur ^ 1;
    if (t < NT - 1) {
      writeA(nxt);            // A(t+1) -> next buffer (readers finished at last barrier)
      issueB(nxt);            // B(t+1) in flight, overlaps MFMA below
      if (t < NT - 2) loadA();// A(t+2) -> regs, overlaps MFMA below
    }
    const char* Ab = smem + cur * 65536;
    const char* Bb = smem + cur * 65536 + 32768;
    #pragma unroll
    for (int ksub = 0; ksub < 2; ++ksub) {
      f16x8 af[8], bfr[4];
      #pragma unroll
      for (int m = 0; m < 8; ++m)
        af[m] = *(const f16x8*)(Ab + (wm * 128 + m * 16 + lrow) * 128
                                   + (((ksub * 4 + lk) ^ (lrow & 7)) * 16));
      #pragma unroll
      for (int n = 0; n < 4; ++n)
        bfr[n] = *(const f16x8*)(Bb + (wn * 64 + n * 16 + lrow) * 128
                                    + (((ksub * 4 + lk) ^ (lrow & 7)) * 16));
      #pragma unroll
      for (int m = 0; m < 8; ++m)
        #pragma unroll
        for (int n = 0; n < 4; ++n)
          acc[m][n] = __builtin_amdgcn_mfma_f32_16x16x32_f16(af[m], bfr[n], acc[m][n], 0, 0, 0);
    }
    __syncthreads();          // drains vmcnt/lgkm: buf[nxt] complete for next iter
  }

  // epilogue: write fp32 partials [color*KSPLIT+ksp][8192][256]
  float* pbase = partials + ((uint64_t)(cc * KSPLIT + ksp) * NROWS + m0) * ACCH;
  #pragma unroll
  for (int m = 0; m < 8; ++m) {
    #pragma unroll
    for (int n = 0; n < 4; ++n) {
      int row = wm * 128 + m * 16 + lk * 4;
      int col = wn * 64 + n * 16 + lrow;
      float* dst = pbase + (uint64_t)row * ACCH + col;
      dst[0]        = acc[m][n][0];
      dst[ACCH]     = acc[m][n][1];
      dst[2 * ACCH] = acc[m][n][2];
      dst[3 * ACCH] = acc[m][n][3];
    }
  }
}

// ---------------- kernel 3: reduce partials + stm-mix + clip + MLP tail (all fp32) ----
// 512 blocks x 128 threads; each block: 16 rows.
__global__ __launch_bounds__(128) void tail_kernel(
    const float* __restrict__ partials, const float* __restrict__ stm,
    const float* __restrict__ bw, const float* __restrict__ bb,
    const float* __restrict__ w1, const float* __restrict__ b1,
    const float* __restrict__ w2, const float* __restrict__ b2,
    const float* __restrict__ w_out, const float* __restrict__ b_out,
    float* __restrict__ out)
{
  __shared__ float in1[16 * 513];   // pitch 513: conflict-free cross-row reads
  __shared__ float out1c[16 * 33];
  const int t = threadIdx.x;
  const int b0 = blockIdx.x * 16;

  // phase 1: reduce split-K partials, stm-mix, clip -> in1[16][512]
  for (int it = 0; it < 32; ++it) {
    int item = t + it * 128;        // 0..4095
    int jc = item & 255;
    int rr = item >> 8;             // 0..15
    int b  = b0 + rr;
    float wsum = bw[jc], bsum = bb[jc];
    #pragma unroll
    for (int k = 0; k < KSPLIT; ++k) {
      wsum += partials[((uint64_t)(0 * KSPLIT + k) * NROWS + b) * ACCH + jc];
      bsum += partials[((uint64_t)(1 * KSPLIT + k) * NROWS + b) * ACCH + jc];
    }
    float s = stm[b];
    float lo = (1.f - s) * wsum + s * bsum;
    float hi = (1.f - s) * bsum + s * wsum;
    in1[rr * 513 + jc]       = fminf(fmaxf(lo, 0.f), 1.f);
    in1[rr * 513 + 256 + jc] = fminf(fmaxf(hi, 0.f), 1.f);
  }
  __syncthreads();

  // layer 1: 512 -> 32, thread (row rl, o-group og) computes o = og*4+oi
  const int rl = t >> 3, og = t & 7;
  float a1[4] = {0.f, 0.f, 0.f, 0.f};
  for (int j = 0; j < 512; j += 4) {
    float v0 = in1[rl * 513 + j];
    float v1 = in1[rl * 513 + j + 1];
    float v2 = in1[rl * 513 + j + 2];
    float v3 = in1[rl * 513 + j + 3];
    #pragma unroll
    for (int oi = 0; oi < 4; ++oi) {
      const float4 wv = *(const float4*)(w1 + (og * 4 + oi) * 512 + j);
      a1[oi] += v0 * wv.x + v1 * wv.y + v2 * wv.z + v3 * wv.w;
    }
  }
  #pragma unroll
  for (int oi = 0; oi < 4; ++oi) {
    int o = og * 4 + oi;
    out1c[rl * 33 + o] = fminf(fmaxf(a1[oi] + b1[o], 0.f), 1.f);
  }
  __syncthreads();

  // layer 2: 32 -> 32
  float a2[4] = {0.f, 0.f, 0.f, 0.f};
  for (int j = 0; j < 32; ++j) {
    float v = out1c[rl * 33 + j];
    #pragma unroll
    for (int oi = 0; oi < 4; ++oi) a2[oi] += v * w2[(og * 4 + oi) * 32 + j];
  }
  // layer 3: 32 -> 1 (clip then dot w_out), reduce across the 8 og lanes
  float p = 0.f;
  #pragma unroll
  for (int oi = 0; oi < 4; ++oi) {
    int o = og * 4 + oi;
    p += fminf(fmaxf(a2[oi] + b2[o], 0.f), 1.f) * w_out[o];
  }
  p += __shfl_xor(p, 1, 64);
  p += __shfl_xor(p, 2, 64);
  p += __shfl_xor(p, 4, 64);
  if (og == 0) out[b0 + rl] = p + b_out[0];
}

extern "C" void kernel_launch(void* const* d_in, const int* in_sizes, int n_in,
                              void* d_out, int out_size, void* d_ws, size_t ws_size,
                              hipStream_t stream) {
  (void)in_sizes; (void)n_in; (void)out_size; (void)ws_size;
  const float* wfeat   = (const float*)d_in[0];
  const float* bfeat   = (const float*)d_in[1];
  const float* stm     = (const float*)d_in[2];
  const float* w_white = (const float*)d_in[3];
  const float* b_white = (const float*)d_in[4];
  const float* w_black = (const float*)d_in[5];
  const float* b_black = (const float*)d_in[6];
  const float* w1      = (const float*)d_in[7];
  const float* b1      = (const float*)d_in[8];
  const float* w2      = (const float*)d_in[9];
  const float* b2      = (const float*)d_in[10];
  const float* w_out   = (const float*)d_in[11];
  const float* b_out   = (const float*)d_in[12];
  float* out = (float*)d_out;

  uint16_t* wf16     = (uint16_t*)d_ws;                                   // 41,943,040 B
  float*    partials = (float*)((char*)d_ws + (uint64_t)2 * ACCH * K_DIM * 2); // 67,108,864 B

  // kernel 1: weights fp32 -> fp16 (2*256*40960 / 8 per thread = 2,621,440 threads)
  convert_w_kernel<<<10240, 256, 0, stream>>>(w_white, w_black, wf16);

  // kernel 2: main GEMM, 128 KiB dynamic LDS
  (void)hipFuncSetAttribute((const void*)ft_gemm,
                            hipFuncAttributeMaxDynamicSharedMemorySize, 131072);
  ft_gemm<<<256, 512, 131072, stream>>>(wfeat, bfeat, wf16, partials);

  // kernel 3: fused reduce + mix + clip + MLP
  tail_kernel<<<512, 128, 0, stream>>>(partials, stm, b_white, b_black,
                                       w1, b1, w2, b2, w_out, b_out, out);
}

// Round 5
// 610.046 us; speedup vs baseline: 1.1874x; 1.0604x over previous
//
#include <hip/hip_runtime.h>
#include <hip/hip_bf16.h>
#include <stdint.h>

#define K_DIM 40960
#define NROWS 8192
#define ACCH 256
#define KSPLIT 4
#define KCHUNK (K_DIM / KSPLIT)   // 10240
#define BM 256
#define BK 64
#define NT (KCHUNK / BK)          // 160

typedef float f32x4 __attribute__((ext_vector_type(4)));
typedef _Float16 f16x8 __attribute__((ext_vector_type(8)));

// RNE f32 -> f16 pair pack (v_cvt_f16_f32 is RNE by default; RTZ would bias)
__device__ __forceinline__ uint32_t pack2_f16(float a, float b) {
  _Float16 ha = (_Float16)a, hb = (_Float16)b;
  uint16_t ua = __builtin_bit_cast(uint16_t, ha);
  uint16_t ub = __builtin_bit_cast(uint16_t, hb);
  return (uint32_t)ua | ((uint32_t)ub << 16);
}

__device__ __forceinline__ void gload_lds16(const void* g, void* l) {
  __builtin_amdgcn_global_load_lds((const __attribute__((address_space(1))) uint32_t*)g,
                                   (__attribute__((address_space(3))) uint32_t*)l, 16, 0, 0);
}

// ---------------- kernel 1: fp32 -> fp16 weight conversion (RNE) ----------------
__global__ void convert_w_kernel(const float* __restrict__ ww, const float* __restrict__ wb,
                                 uint16_t* __restrict__ dst) {
  uint32_t gid = blockIdx.x * blockDim.x + threadIdx.x;
  uint64_t e = (uint64_t)gid * 8u;
  const uint64_t half = (uint64_t)ACCH * K_DIM;
  const float* src = (e < half) ? (ww + e) : (wb + (e - half));
  float4 f0 = *(const float4*)src;
  float4 f1 = *(const float4*)(src + 4);
  uint4 o;
  o.x = pack2_f16(f0.x, f0.y);
  o.y = pack2_f16(f0.z, f0.w);
  o.z = pack2_f16(f1.x, f1.y);
  o.w = pack2_f16(f1.z, f1.w);
  *(uint4*)(dst + e) = o;
}

// ---------------- kernel 2: split-K feature-transformer GEMM (fp16 MFMA) ----------
// grid = 256 blocks, 512 threads (8 waves, 2x4). tile 256x256xBK64, dbuf 128 KiB LDS.
// T2 XOR-swizzle on A (swizzled ds_write) and B (pre-swizzled global source, rule #21).
// T4 counted vmcnt, FIXED ordering vs round 4: issueB(t+1) -> writeA(t+1) [consumes
// av loaded LAST iter; compiler inserts vmcnt(4), no drain] -> loadA(t+2) [issued
// after B]. Barrier waits vmcnt(8): retires exactly B(t+1) (in-order), A(t+2)
// stays in flight across the barrier. Last 2 iters drain to 0.
__global__ __launch_bounds__(512, 2) void ft_gemm(
    const float* __restrict__ featW, const float* __restrict__ featB,
    const uint16_t* __restrict__ wts, float* __restrict__ partials)
{
  extern __shared__ char smem[];
  const int tid = threadIdx.x;
  const int bid = blockIdx.x;
  // XCD-aware remap: (cc,ksp) = bid&7 so same B-panel stays on one XCD's L2
  const int mt  = bid >> 3;
  const int cc  = bid & 1;
  const int ksp = (bid >> 1) & 3;
  const float*    feat = cc ? featB : featW;
  const uint16_t* wp   = wts + (uint64_t)cc * ACCH * K_DIM;
  const int m0 = mt * BM;
  const int k0 = ksp * KCHUNK;

  const int wid  = tid >> 6;
  const int lane = tid & 63;
  const int wm   = wid >> 2;   // 0..1
  const int wn   = wid & 3;    // 0..3
  const int lrow = lane & 15;
  const int lk   = lane >> 4;  // 0..3

  // A staging: 4 segments of 8 floats per thread; segment p = base + p*64 rows
  const int ar0 = tid >> 3, as0 = tid & 7;
  const float* aSrc0 = feat + (uint64_t)(m0 + ar0) * K_DIM + k0 + as0 * 8;
  // swizzled LDS byte offset: slot as0 ^ (row&7), row pitch 128B
  const int aOff0 = ar0 * 128 + ((as0 ^ (ar0 & 7)) * 16);

  // B staging: 4 global_load_lds(16B) per thread; instr i = base + i*64 rows.
  // LDS dest linear; global source pre-swizzled: chunk = (l&7) ^ (row&7)
  const int gsegB = wid * 64 + lane;
  const int br0 = gsegB >> 3;
  const int bs0 = (gsegB & 7) ^ (br0 & 7);
  const uint16_t* bSrc0 = wp + (uint64_t)br0 * K_DIM + k0 + bs0 * 8;

  float4 av[4][2];
  auto loadA = [&]() {
    #pragma unroll
    for (int p = 0; p < 4; ++p) {
      const float* s = aSrc0 + (uint64_t)p * 64u * K_DIM;
      av[p][0] = *(const float4*)(s);
      av[p][1] = *(const float4*)(s + 4);
    }
    aSrc0 += BK;
  };
  auto writeA = [&](int buf) {
    #pragma unroll
    for (int p = 0; p < 4; ++p) {
      uint4 o;
      o.x = pack2_f16(av[p][0].x, av[p][0].y);
      o.y = pack2_f16(av[p][0].z, av[p][0].w);
      o.z = pack2_f16(av[p][1].x, av[p][1].y);
      o.w = pack2_f16(av[p][1].z, av[p][1].w);
      *(uint4*)(smem + buf * 65536 + aOff0 + p * 8192) = o;
    }
  };
  auto issueB = [&](int buf) {
    #pragma unroll
    for (int i = 0; i < 4; ++i) {
      gload_lds16(bSrc0 + (uint64_t)i * 64u * K_DIM,
                  smem + buf * 65536 + 32768 + (i * 8 + wid) * 1024);
    }
    bSrc0 += BK;
  };

  // prologue: A(0) -> regs; B(0) -> buf0; cvt A(0) -> buf0; A(1) -> regs; drain.
  loadA();
  issueB(0);
  writeA(0);
  loadA();
  __syncthreads();

  f32x4 acc[8][4];
  #pragma unroll
  for (int m = 0; m < 8; ++m)
    #pragma unroll
    for (int n = 0; n < 4; ++n)
      acc[m][n] = (f32x4){0.f, 0.f, 0.f, 0.f};

  for (int t = 0; t < NT; ++t) {
    const int cur = t & 1, nxt = cur ^ 1;
    // VMEM issue order pinned: B(t+1) first (oldest), then A(t+2).
    // writeA consumes av = A(t+1) BEFORE loadA overwrites it (round-4 bug fix).
    if (t < NT - 1) issueB(nxt);
    asm volatile("" ::: "memory");
    if (t < NT - 1) writeA(nxt);   // compiler emits vmcnt(4): waits A(t+1) only
    asm volatile("" ::: "memory");
    if (t < NT - 2) loadA();       // A(t+2): 8 loads, stay in flight past barrier
    asm volatile("" ::: "memory");

    const char* Ab = smem + cur * 65536;
    const char* Bb = smem + cur * 65536 + 32768;
    #pragma unroll
    for (int ksub = 0; ksub < 2; ++ksub) {
      f16x8 af[8], bfr[4];
      #pragma unroll
      for (int m = 0; m < 8; ++m)
        af[m] = *(const f16x8*)(Ab + (wm * 128 + m * 16 + lrow) * 128
                                   + (((ksub * 4 + lk) ^ (lrow & 7)) * 16));
      #pragma unroll
      for (int n = 0; n < 4; ++n)
        bfr[n] = *(const f16x8*)(Bb + (wn * 64 + n * 16 + lrow) * 128
                                    + (((ksub * 4 + lk) ^ (lrow & 7)) * 16));
      #pragma unroll
      for (int m = 0; m < 8; ++m)
        #pragma unroll
        for (int n = 0; n < 4; ++n)
          acc[m][n] = __builtin_amdgcn_mfma_f32_16x16x32_f16(af[m], bfr[n], acc[m][n], 0, 0, 0);
    }

    // counted-vmcnt barrier: outstanding = B(t+1)[4 oldest] + A(t+2)[8];
    // vmcnt(8) retires exactly B(t+1). At t >= NT-2 only B remains -> drain 0.
    if (t < NT - 2) {
      asm volatile("s_waitcnt vmcnt(8) lgkmcnt(0)" ::: "memory");
    } else {
      asm volatile("s_waitcnt vmcnt(0) lgkmcnt(0)" ::: "memory");
    }
    __builtin_amdgcn_s_barrier();
  }

  // epilogue: write fp32 partials [color*KSPLIT+ksp][8192][256]
  float* pbase = partials + ((uint64_t)(cc * KSPLIT + ksp) * NROWS + m0) * ACCH;
  #pragma unroll
  for (int m = 0; m < 8; ++m) {
    #pragma unroll
    for (int n = 0; n < 4; ++n) {
      int row = wm * 128 + m * 16 + lk * 4;
      int col = wn * 64 + n * 16 + lrow;
      float* dst = pbase + (uint64_t)row * ACCH + col;
      dst[0]        = acc[m][n][0];
      dst[ACCH]     = acc[m][n][1];
      dst[2 * ACCH] = acc[m][n][2];
      dst[3 * ACCH] = acc[m][n][3];
    }
  }
}

// ---------------- kernel 3: reduce partials + stm-mix + clip + MLP tail (all fp32) ----
// 512 blocks x 128 threads; each block: 16 rows.
__global__ __launch_bounds__(128) void tail_kernel(
    const float* __restrict__ partials, const float* __restrict__ stm,
    const float* __restrict__ bw, const float* __restrict__ bb,
    const float* __restrict__ w1, const float* __restrict__ b1,
    const float* __restrict__ w2, const float* __restrict__ b2,
    const float* __restrict__ w_out, const float* __restrict__ b_out,
    float* __restrict__ out)
{
  __shared__ float in1[16 * 513];   // pitch 513: conflict-free cross-row reads
  __shared__ float out1c[16 * 33];
  const int t = threadIdx.x;
  const int b0 = blockIdx.x * 16;

  // phase 1: reduce split-K partials, stm-mix, clip -> in1[16][512]
  for (int it = 0; it < 32; ++it) {
    int item = t + it * 128;        // 0..4095
    int jc = item & 255;
    int rr = item >> 8;             // 0..15
    int b  = b0 + rr;
    float wsum = bw[jc], bsum = bb[jc];
    #pragma unroll
    for (int k = 0; k < KSPLIT; ++k) {
      wsum += partials[((uint64_t)(0 * KSPLIT + k) * NROWS + b) * ACCH + jc];
      bsum += partials[((uint64_t)(1 * KSPLIT + k) * NROWS + b) * ACCH + jc];
    }
    float s = stm[b];
    float lo = (1.f - s) * wsum + s * bsum;
    float hi = (1.f - s) * bsum + s * wsum;
    in1[rr * 513 + jc]       = fminf(fmaxf(lo, 0.f), 1.f);
    in1[rr * 513 + 256 + jc] = fminf(fmaxf(hi, 0.f), 1.f);
  }
  __syncthreads();

  // layer 1: 512 -> 32, thread (row rl, o-group og) computes o = og*4+oi
  const int rl = t >> 3, og = t & 7;
  float a1[4] = {0.f, 0.f, 0.f, 0.f};
  for (int j = 0; j < 512; j += 4) {
    float v0 = in1[rl * 513 + j];
    float v1 = in1[rl * 513 + j + 1];
    float v2 = in1[rl * 513 + j + 2];
    float v3 = in1[rl * 513 + j + 3];
    #pragma unroll
    for (int oi = 0; oi < 4; ++oi) {
      const float4 wv = *(const float4*)(w1 + (og * 4 + oi) * 512 + j);
      a1[oi] += v0 * wv.x + v1 * wv.y + v2 * wv.z + v3 * wv.w;
    }
  }
  #pragma unroll
  for (int oi = 0; oi < 4; ++oi) {
    int o = og * 4 + oi;
    out1c[rl * 33 + o] = fminf(fmaxf(a1[oi] + b1[o], 0.f), 1.f);
  }
  __syncthreads();

  // layer 2: 32 -> 32
  float a2[4] = {0.f, 0.f, 0.f, 0.f};
  for (int j = 0; j < 32; ++j) {
    float v = out1c[rl * 33 + j];
    #pragma unroll
    for (int oi = 0; oi < 4; ++oi) a2[oi] += v * w2[(og * 4 + oi) * 32 + j];
  }
  // layer 3: 32 -> 1 (clip then dot w_out), reduce across the 8 og lanes
  float p = 0.f;
  #pragma unroll
  for (int oi = 0; oi < 4; ++oi) {
    int o = og * 4 + oi;
    p += fminf(fmaxf(a2[oi] + b2[o], 0.f), 1.f) * w_out[o];
  }
  p += __shfl_xor(p, 1, 64);
  p += __shfl_xor(p, 2, 64);
  p += __shfl_xor(p, 4, 64);
  if (og == 0) out[b0 + rl] = p + b_out[0];
}

extern "C" void kernel_launch(void* const* d_in, const int* in_sizes, int n_in,
                              void* d_out, int out_size, void* d_ws, size_t ws_size,
                              hipStream_t stream) {
  (void)in_sizes; (void)n_in; (void)out_size; (void)ws_size;
  const float* wfeat   = (const float*)d_in[0];
  const float* bfeat   = (const float*)d_in[1];
  const float* stm     = (const float*)d_in[2];
  const float* w_white = (const float*)d_in[3];
  const float* b_white = (const float*)d_in[4];
  const float* w_black = (const float*)d_in[5];
  const float* b_black = (const float*)d_in[6];
  const float* w1      = (const float*)d_in[7];
  const float* b1      = (const float*)d_in[8];
  const float* w2      = (const float*)d_in[9];
  const float* b2      = (const float*)d_in[10];
  const float* w_out   = (const float*)d_in[11];
  const float* b_out   = (const float*)d_in[12];
  float* out = (float*)d_out;

  uint16_t* wf16     = (uint16_t*)d_ws;                                   // 41,943,040 B
  float*    partials = (float*)((char*)d_ws + (uint64_t)2 * ACCH * K_DIM * 2); // 67,108,864 B

  // kernel 1: weights fp32 -> fp16 (2*256*40960 / 8 per thread = 2,621,440 threads)
  convert_w_kernel<<<10240, 256, 0, stream>>>(w_white, w_black, wf16);

  // kernel 2: main GEMM, 128 KiB dynamic LDS
  (void)hipFuncSetAttribute((const void*)ft_gemm,
                            hipFuncAttributeMaxDynamicSharedMemorySize, 131072);
  ft_gemm<<<256, 512, 131072, stream>>>(wfeat, bfeat, wf16, partials);

  // kernel 3: fused reduce + mix + clip + MLP
  tail_kernel<<<512, 128, 0, stream>>>(partials, stm, b_white, b_black,
                                       w1, b1, w2, b2, w_out, b_out, out);
}

// Round 6
// 609.329 us; speedup vs baseline: 1.1888x; 1.0012x over previous
//
#include <hip/hip_runtime.h>
#include <hip/hip_bf16.h>
#include <stdint.h>

#define K_DIM 40960
#define NROWS 8192
#define ACCH 256
#define KSPLIT 4
#define KCHUNK (K_DIM / KSPLIT)   // 10240
#define BM 256
#define BK 64
#define NT (KCHUNK / BK)          // 160

typedef float f32x4 __attribute__((ext_vector_type(4)));
typedef _Float16 f16x8 __attribute__((ext_vector_type(8)));

// RNE f32 -> f16 pair pack (v_cvt_f16_f32 is RNE by default; RTZ would bias)
__device__ __forceinline__ uint32_t pack2_f16(float a, float b) {
  _Float16 ha = (_Float16)a, hb = (_Float16)b;
  uint16_t ua = __builtin_bit_cast(uint16_t, ha);
  uint16_t ub = __builtin_bit_cast(uint16_t, hb);
  return (uint32_t)ua | ((uint32_t)ub << 16);
}

__device__ __forceinline__ void gload_lds16(const void* g, void* l) {
  __builtin_amdgcn_global_load_lds((const __attribute__((address_space(1))) uint32_t*)g,
                                   (__attribute__((address_space(3))) uint32_t*)l, 16, 0, 0);
}

// ---------------- kernel 1: fp32 -> fp16 weight conversion (RNE) ----------------
__global__ void convert_w_kernel(const float* __restrict__ ww, const float* __restrict__ wb,
                                 uint16_t* __restrict__ dst) {
  uint32_t gid = blockIdx.x * blockDim.x + threadIdx.x;
  uint64_t e = (uint64_t)gid * 8u;
  const uint64_t half = (uint64_t)ACCH * K_DIM;
  const float* src = (e < half) ? (ww + e) : (wb + (e - half));
  float4 f0 = *(const float4*)src;
  float4 f1 = *(const float4*)(src + 4);
  uint4 o;
  o.x = pack2_f16(f0.x, f0.y);
  o.y = pack2_f16(f0.z, f0.w);
  o.z = pack2_f16(f1.x, f1.y);
  o.w = pack2_f16(f1.z, f1.w);
  *(uint4*)(dst + e) = o;
}

// ---------------- kernel 2: split-K feature-transformer GEMM (fp16 MFMA) ----------
// grid = 256 blocks, 512 threads (8 waves, 2x4). tile 256x256xBK64.
// LDS 160 KiB: A double-buffer 2x32K @ 0, B TRIPLE-buffer 3x32K @ 64K.
// T2 XOR-swizzle on A (swizzled ds_write) and B (pre-swizzled global source, rule #21).
// Schedule per iter t: issueB(t+2) -> writeA(t+1) [compiler vmcnt(4) waits A(t+1);
// in-order retirement also retires B(t+1), giving B a FULL iteration of slack]
// -> loadA(t+2) -> MFMA on (Ab[t&1], Bb[t%3]) -> lgkmcnt(0)-only barrier
// (no vmcnt at the barrier: B(t+2)+A(t+2) stream across it).
__global__ __launch_bounds__(512, 2) void ft_gemm(
    const float* __restrict__ featW, const float* __restrict__ featB,
    const uint16_t* __restrict__ wts, float* __restrict__ partials)
{
  extern __shared__ char smem[];
  const int tid = threadIdx.x;
  const int bid = blockIdx.x;
  // XCD-aware remap: (cc,ksp) = bid&7 so same B-panel stays on one XCD's L2
  const int mt  = bid >> 3;
  const int cc  = bid & 1;
  const int ksp = (bid >> 1) & 3;
  const float*    feat = cc ? featB : featW;
  const uint16_t* wp   = wts + (uint64_t)cc * ACCH * K_DIM;
  const int m0 = mt * BM;
  const int k0 = ksp * KCHUNK;

  const int wid  = tid >> 6;
  const int lane = tid & 63;
  const int wm   = wid >> 2;   // 0..1
  const int wn   = wid & 3;    // 0..3
  const int lrow = lane & 15;
  const int lk   = lane >> 4;  // 0..3

  // A staging: 4 segments of 8 floats per thread; segment p = base + p*64 rows
  const int ar0 = tid >> 3, as0 = tid & 7;
  const float* aSrc0 = feat + (uint64_t)(m0 + ar0) * K_DIM + k0 + as0 * 8;
  // swizzled LDS byte offset: slot as0 ^ (row&7), row pitch 128B
  const int aOff0 = ar0 * 128 + ((as0 ^ (ar0 & 7)) * 16);

  // B staging: 4 global_load_lds(16B) per thread; instr i = base + i*64 rows.
  // LDS dest linear; global source pre-swizzled: chunk = (l&7) ^ (row&7)
  const int gsegB = wid * 64 + lane;
  const int br0 = gsegB >> 3;
  const int bs0 = (gsegB & 7) ^ (br0 & 7);
  const uint16_t* bSrc0 = wp + (uint64_t)br0 * K_DIM + k0 + bs0 * 8;

  float4 av[4][2];
  auto loadA = [&]() {
    #pragma unroll
    for (int p = 0; p < 4; ++p) {
      const float* s = aSrc0 + (uint64_t)p * 64u * K_DIM;
      av[p][0] = *(const float4*)(s);
      av[p][1] = *(const float4*)(s + 4);
    }
    aSrc0 += BK;
  };
  auto writeA = [&](int buf) {   // buf in {0,1}, 32 KB each at offset 0
    #pragma unroll
    for (int p = 0; p < 4; ++p) {
      uint4 o;
      o.x = pack2_f16(av[p][0].x, av[p][0].y);
      o.y = pack2_f16(av[p][0].z, av[p][0].w);
      o.z = pack2_f16(av[p][1].x, av[p][1].y);
      o.w = pack2_f16(av[p][1].z, av[p][1].w);
      *(uint4*)(smem + buf * 32768 + aOff0 + p * 8192) = o;
    }
  };
  auto issueB = [&](int buf) {   // buf in {0,1,2}, 32 KB each at offset 64K
    #pragma unroll
    for (int i = 0; i < 4; ++i) {
      gload_lds16(bSrc0 + (uint64_t)i * 64u * K_DIM,
                  smem + 65536 + buf * 32768 + (i * 8 + wid) * 1024);
    }
    bSrc0 += BK;
  };

  // prologue: A(0); B(0); cvt A(0)->Ab0 [vmcnt(4) leaves B0]; A(1); B(1);
  // wait B(0) done (vmcnt(12): leaves A1+B1) + A ds_writes visible.
  loadA();
  issueB(0);
  writeA(0);
  loadA();
  issueB(1);
  asm volatile("s_waitcnt vmcnt(12) lgkmcnt(0)" ::: "memory");
  __builtin_amdgcn_s_barrier();

  f32x4 acc[8][4];
  #pragma unroll
  for (int m = 0; m < 8; ++m)
    #pragma unroll
    for (int n = 0; n < 4; ++n)
      acc[m][n] = (f32x4){0.f, 0.f, 0.f, 0.f};

  int bcur = 0;                    // t % 3
  for (int t = 0; t < NT; ++t) {
    const int acur = t & 1;
    const int bnx2 = (bcur >= 1) ? bcur - 1 : bcur + 2;   // (t+2) % 3
    // VMEM issue order pinned: B(t+2) first, then (after writeA) A(t+2).
    if (t < NT - 2) issueB(bnx2);
    asm volatile("" ::: "memory");
    if (t < NT - 1) writeA(acur ^ 1);  // consumes av=A(t+1); compiler waits vmcnt(4)
    asm volatile("" ::: "memory");
    if (t < NT - 2) loadA();           // av = A(t+2), stays in flight past barrier
    asm volatile("" ::: "memory");

    const char* Ab = smem + acur * 32768;
    const char* Bb = smem + 65536 + bcur * 32768;
    #pragma unroll
    for (int ksub = 0; ksub < 2; ++ksub) {
      f16x8 af[8], bfr[4];
      #pragma unroll
      for (int m = 0; m < 8; ++m)
        af[m] = *(const f16x8*)(Ab + (wm * 128 + m * 16 + lrow) * 128
                                   + (((ksub * 4 + lk) ^ (lrow & 7)) * 16));
      #pragma unroll
      for (int n = 0; n < 4; ++n)
        bfr[n] = *(const f16x8*)(Bb + (wn * 64 + n * 16 + lrow) * 128
                                    + (((ksub * 4 + lk) ^ (lrow & 7)) * 16));
      #pragma unroll
      for (int m = 0; m < 8; ++m)
        #pragma unroll
        for (int n = 0; n < 4; ++n)
          acc[m][n] = __builtin_amdgcn_mfma_f32_16x16x32_f16(af[m], bfr[n], acc[m][n], 0, 0, 0);
    }

    // barrier with NO vmcnt: B(t+1) already retired by writeA's in-order wait;
    // lgkmcnt(0) makes this iter's A ds_writes visible to all waves.
    asm volatile("s_waitcnt lgkmcnt(0)" ::: "memory");
    __builtin_amdgcn_s_barrier();
    bcur = (bcur >= 2) ? 0 : bcur + 1;
  }

  // epilogue: write fp32 partials [color*KSPLIT+ksp][8192][256]
  float* pbase = partials + ((uint64_t)(cc * KSPLIT + ksp) * NROWS + m0) * ACCH;
  #pragma unroll
  for (int m = 0; m < 8; ++m) {
    #pragma unroll
    for (int n = 0; n < 4; ++n) {
      int row = wm * 128 + m * 16 + lk * 4;
      int col = wn * 64 + n * 16 + lrow;
      float* dst = pbase + (uint64_t)row * ACCH + col;
      dst[0]        = acc[m][n][0];
      dst[ACCH]     = acc[m][n][1];
      dst[2 * ACCH] = acc[m][n][2];
      dst[3 * ACCH] = acc[m][n][3];
    }
  }
}

// ---------------- kernel 3: reduce partials + stm-mix + clip + MLP tail (all fp32) ----
// 512 blocks x 128 threads; each block: 16 rows.
__global__ __launch_bounds__(128) void tail_kernel(
    const float* __restrict__ partials, const float* __restrict__ stm,
    const float* __restrict__ bw, const float* __restrict__ bb,
    const float* __restrict__ w1, const float* __restrict__ b1,
    const float* __restrict__ w2, const float* __restrict__ b2,
    const float* __restrict__ w_out, const float* __restrict__ b_out,
    float* __restrict__ out)
{
  __shared__ float in1[16 * 513];   // pitch 513: conflict-free cross-row reads
  __shared__ float out1c[16 * 33];
  const int t = threadIdx.x;
  const int b0 = blockIdx.x * 16;

  // phase 1: reduce split-K partials, stm-mix, clip -> in1[16][512]
  for (int it = 0; it < 32; ++it) {
    int item = t + it * 128;        // 0..4095
    int jc = item & 255;
    int rr = item >> 8;             // 0..15
    int b  = b0 + rr;
    float wsum = bw[jc], bsum = bb[jc];
    #pragma unroll
    for (int k = 0; k < KSPLIT; ++k) {
      wsum += partials[((uint64_t)(0 * KSPLIT + k) * NROWS + b) * ACCH + jc];
      bsum += partials[((uint64_t)(1 * KSPLIT + k) * NROWS + b) * ACCH + jc];
    }
    float s = stm[b];
    float lo = (1.f - s) * wsum + s * bsum;
    float hi = (1.f - s) * bsum + s * wsum;
    in1[rr * 513 + jc]       = fminf(fmaxf(lo, 0.f), 1.f);
    in1[rr * 513 + 256 + jc] = fminf(fmaxf(hi, 0.f), 1.f);
  }
  __syncthreads();

  // layer 1: 512 -> 32, thread (row rl, o-group og) computes o = og*4+oi
  const int rl = t >> 3, og = t & 7;
  float a1[4] = {0.f, 0.f, 0.f, 0.f};
  for (int j = 0; j < 512; j += 4) {
    float v0 = in1[rl * 513 + j];
    float v1 = in1[rl * 513 + j + 1];
    float v2 = in1[rl * 513 + j + 2];
    float v3 = in1[rl * 513 + j + 3];
    #pragma unroll
    for (int oi = 0; oi < 4; ++oi) {
      const float4 wv = *(const float4*)(w1 + (og * 4 + oi) * 512 + j);
      a1[oi] += v0 * wv.x + v1 * wv.y + v2 * wv.z + v3 * wv.w;
    }
  }
  #pragma unroll
  for (int oi = 0; oi < 4; ++oi) {
    int o = og * 4 + oi;
    out1c[rl * 33 + o] = fminf(fmaxf(a1[oi] + b1[o], 0.f), 1.f);
  }
  __syncthreads();

  // layer 2: 32 -> 32
  float a2[4] = {0.f, 0.f, 0.f, 0.f};
  for (int j = 0; j < 32; ++j) {
    float v = out1c[rl * 33 + j];
    #pragma unroll
    for (int oi = 0; oi < 4; ++oi) a2[oi] += v * w2[(og * 4 + oi) * 32 + j];
  }
  // layer 3: 32 -> 1 (clip then dot w_out), reduce across the 8 og lanes
  float p = 0.f;
  #pragma unroll
  for (int oi = 0; oi < 4; ++oi) {
    int o = og * 4 + oi;
    p += fminf(fmaxf(a2[oi] + b2[o], 0.f), 1.f) * w_out[o];
  }
  p += __shfl_xor(p, 1, 64);
  p += __shfl_xor(p, 2, 64);
  p += __shfl_xor(p, 4, 64);
  if (og == 0) out[b0 + rl] = p + b_out[0];
}

extern "C" void kernel_launch(void* const* d_in, const int* in_sizes, int n_in,
                              void* d_out, int out_size, void* d_ws, size_t ws_size,
                              hipStream_t stream) {
  (void)in_sizes; (void)n_in; (void)out_size; (void)ws_size;
  const float* wfeat   = (const float*)d_in[0];
  const float* bfeat   = (const float*)d_in[1];
  const float* stm     = (const float*)d_in[2];
  const float* w_white = (const float*)d_in[3];
  const float* b_white = (const float*)d_in[4];
  const float* w_black = (const float*)d_in[5];
  const float* b_black = (const float*)d_in[6];
  const float* w1      = (const float*)d_in[7];
  const float* b1      = (const float*)d_in[8];
  const float* w2      = (const float*)d_in[9];
  const float* b2      = (const float*)d_in[10];
  const float* w_out   = (const float*)d_in[11];
  const float* b_out   = (const float*)d_in[12];
  float* out = (float*)d_out;

  uint16_t* wf16     = (uint16_t*)d_ws;                                   // 41,943,040 B
  float*    partials = (float*)((char*)d_ws + (uint64_t)2 * ACCH * K_DIM * 2); // 67,108,864 B

  // kernel 1: weights fp32 -> fp16 (2*256*40960 / 8 per thread = 2,621,440 threads)
  convert_w_kernel<<<10240, 256, 0, stream>>>(w_white, w_black, wf16);

  // kernel 2: main GEMM, 160 KiB dynamic LDS (2x32K A-dbuf + 3x32K B-tribuf)
  (void)hipFuncSetAttribute((const void*)ft_gemm,
                            hipFuncAttributeMaxDynamicSharedMemorySize, 163840);
  ft_gemm<<<256, 512, 163840, stream>>>(wfeat, bfeat, wf16, partials);

  // kernel 3: fused reduce + mix + clip + MLP
  tail_kernel<<<512, 128, 0, stream>>>(partials, stm, b_white, b_black,
                                       w1, b1, w2, b2, w_out, b_out, out);
}